// Round 1
// baseline (49120.435 us; speedup 1.0000x reference)
//
#include <hip/hip_runtime.h>
#include <math.h>

constexpr int L = 4, H = 768, NH = 12, DH = 64, FF = 3072;
constexpr int B = 4, S = 1024;
constexpr int BS = B * S;          // 4096 token rows
constexpr float EPS = 1e-5f;
constexpr float SCALE = 0.125f;    // 1/sqrt(DH)

// ---------------- prep: RoPE tables + bbox floats + mask bias ----------------
__global__ void prep_kernel(const int* __restrict__ bbox, const int* __restrict__ mask,
                            float* __restrict__ st1, float* __restrict__ ct1,
                            float* __restrict__ st2, float* __restrict__ ct2,
                            float* __restrict__ xs1, float* __restrict__ xs2,
                            float* __restrict__ xcA, float* __restrict__ ycA,
                            float* __restrict__ mb)
{
    int idx = blockIdx.x * blockDim.x + threadIdx.x;
    if (idx >= BS) return;
    int4 bb = ((const int4*)bbox)[idx];
    float x1 = (float)bb.x, y1 = (float)bb.y, x2 = (float)bb.z, y2 = (float)bb.w;
    xs1[idx] = x1; xs2[idx] = x2;
    xcA[idx] = (x1 + x2) * 0.5f; ycA[idx] = (y1 + y2) * 0.5f;
    mb[idx] = (1.0f - (float)mask[idx]) * -10000.0f;
    #pragma unroll
    for (int fm = 0; fm < 16; ++fm) {
        // inv_freq = 10000^(-2*fm/32)
        float f = powf(10000.0f, -(float)(2 * fm) / 32.0f);
        float a;
        a = x1 * f; st1[idx*32 + 2*fm]     = sinf(a); ct1[idx*32 + 2*fm]     = cosf(a);
        a = y1 * f; st1[idx*32 + 2*fm + 1] = sinf(a); ct1[idx*32 + 2*fm + 1] = cosf(a);
        a = x2 * f; st2[idx*32 + 2*fm]     = sinf(a); ct2[idx*32 + 2*fm]     = cosf(a);
        a = y2 * f; st2[idx*32 + 2*fm + 1] = sinf(a); ct2[idx*32 + 2*fm + 1] = cosf(a);
    }
}

// ---------------- generic fp32 tiled GEMM: C = A(M,K) @ W(K,N) + bias [+res][+gelu] ----
// EPI: 0 = bias, 1 = bias + residual, 2 = bias + exact GELU
template<int EPI>
__global__ __launch_bounds__(256)
void gemm_kernel(const float* __restrict__ A, const float* __restrict__ W,
                 const float* __restrict__ bias, const float* __restrict__ res,
                 float* __restrict__ C, int M, int N, int K)
{
    __shared__ float As[16][68];   // transposed A tile, +4 pad (keeps 16B align, spreads banks)
    __shared__ float Bs[16][68];
    const int tid = threadIdx.x;
    const int row0 = blockIdx.x * 64, col0 = blockIdx.y * 64;
    const int tm = tid >> 4, tn = tid & 15;
    const int ar = tid >> 2, ac4 = (tid & 3) * 4;        // A tile: 64 rows x 16 k
    const int wr = tid >> 4, wc4 = (tid & 15) * 4;       // W tile: 16 k x 64 cols
    float acc[4][4] = {};

    for (int k0 = 0; k0 < K; k0 += 16) {
        float4 va = *(const float4*)&A[(size_t)(row0 + ar) * K + k0 + ac4];
        float4 vb = *(const float4*)&W[(size_t)(k0 + wr) * N + col0 + wc4];
        __syncthreads();   // previous iteration's compute done before overwrite
        As[ac4 + 0][ar] = va.x; As[ac4 + 1][ar] = va.y;
        As[ac4 + 2][ar] = va.z; As[ac4 + 3][ar] = va.w;
        *(float4*)&Bs[wr][wc4] = vb;
        __syncthreads();
        #pragma unroll
        for (int kk = 0; kk < 16; ++kk) {
            float4 a4 = *(const float4*)&As[kk][tm * 4];
            float4 b4 = *(const float4*)&Bs[kk][tn * 4];
            float av[4] = {a4.x, a4.y, a4.z, a4.w};
            float bv[4] = {b4.x, b4.y, b4.z, b4.w};
            #pragma unroll
            for (int i = 0; i < 4; ++i)
                #pragma unroll
                for (int j = 0; j < 4; ++j)
                    acc[i][j] += av[i] * bv[j];
        }
    }

    float4 bsv = *(const float4*)&bias[col0 + tn * 4];
    float bias4[4] = {bsv.x, bsv.y, bsv.z, bsv.w};
    #pragma unroll
    for (int i = 0; i < 4; ++i) {
        int r = row0 + tm * 4 + i;
        float c[4];
        #pragma unroll
        for (int j = 0; j < 4; ++j) c[j] = acc[i][j] + bias4[j];
        if (EPI == 1) {
            float4 rv = *(const float4*)&res[(size_t)r * N + col0 + tn * 4];
            c[0] += rv.x; c[1] += rv.y; c[2] += rv.z; c[3] += rv.w;
        }
        if (EPI == 2) {
            #pragma unroll
            for (int j = 0; j < 4; ++j)
                c[j] = 0.5f * c[j] * (1.0f + erff(c[j] * 0.70710678118654752f));
        }
        float4 outv = make_float4(c[0], c[1], c[2], c[3]);
        *(float4*)&C[(size_t)r * N + col0 + tn * 4] = outv;
    }
}

// ---------------- 2D interleaved RoPE on q and k (B,S,H layout) ----------------
__global__ void rope_kernel(float* __restrict__ q, float* __restrict__ k,
                            const float* __restrict__ st1, const float* __restrict__ ct1,
                            const float* __restrict__ st2, const float* __restrict__ ct2)
{
    int tid = blockIdx.x * blockDim.x + threadIdx.x;  // over BS*NH*32 pairs
    int pr = tid & 31;
    int nh = (tid >> 5) % NH;
    int bs = tid / (32 * NH);
    const float* st = (nh & 1) ? st2 : st1;   // even heads -> (x1,y1) table
    const float* ct = (nh & 1) ? ct2 : ct1;
    float sv = st[bs * 32 + pr], cv = ct[bs * 32 + pr];
    size_t base = (size_t)bs * H + nh * 64 + pr * 2;
    float2 qv = *(float2*)&q[base];
    float2 kv = *(float2*)&k[base];
    *(float2*)&q[base] = make_float2(qv.x * cv - qv.y * sv, qv.y * cv + qv.x * sv);
    *(float2*)&k[base] = make_float2(kv.x * cv - kv.y * sv, kv.y * cv + kv.x * sv);
}

// ---------------- flash-style attention with bbox-distance bias ----------------
// 1 block = 1 wave = 64 q rows of one (b, head). K/V chunks of 32 staged in LDS.
__global__ __launch_bounds__(64)
void attn_kernel(const float* __restrict__ q, const float* __restrict__ k,
                 const float* __restrict__ v,
                 const float* __restrict__ xs1, const float* __restrict__ xs2,
                 const float* __restrict__ xcA, const float* __restrict__ ycA,
                 const float* __restrict__ mb, float* __restrict__ ctx)
{
    __shared__ float Ks[32][64];
    __shared__ float Vs[32][64];
    __shared__ float bx1[32], bx2[32], bxc[32], byc[32], bmb[32];
    const int lane = threadIdx.x;
    const int qt = blockIdx.x & 15;            // S/64 = 16 q tiles
    const int nh = (blockIdx.x >> 4) % NH;
    const int b  = blockIdx.x / (16 * NH);
    const int qrow = qt * 64 + lane;
    const int bs0 = b * S;
    const size_t qbase = ((size_t)(bs0 + qrow)) * H + nh * 64;

    float4 Q[16];
    #pragma unroll
    for (int i = 0; i < 16; ++i) Q[i] = *(const float4*)&q[qbase + i * 4];
    const float qx1 = xs1[bs0 + qrow], qx2 = xs2[bs0 + qrow];
    const float qxc = xcA[bs0 + qrow], qyc = ycA[bs0 + qrow];

    float m = -1e30f, lsum = 0.0f;
    float4 O[16];
    #pragma unroll
    for (int i = 0; i < 16; ++i) O[i] = make_float4(0.f, 0.f, 0.f, 0.f);

    for (int kc = 0; kc < S; kc += 32) {
        #pragma unroll
        for (int i = 0; i < 8; ++i) {
            int idx = i * 64 + lane;
            int r = idx >> 4, c = (idx & 15) * 4;
            *(float4*)&Ks[r][c] = *(const float4*)&k[((size_t)(bs0 + kc + r)) * H + nh * 64 + c];
            *(float4*)&Vs[r][c] = *(const float4*)&v[((size_t)(bs0 + kc + r)) * H + nh * 64 + c];
        }
        if (lane < 32) {
            bx1[lane] = xs1[bs0 + kc + lane]; bx2[lane] = xs2[bs0 + kc + lane];
            bxc[lane] = xcA[bs0 + kc + lane]; byc[lane] = ycA[bs0 + kc + lane];
            bmb[lane] = mb[bs0 + kc + lane];
        }
        __syncthreads();

        float s[32];
        float cmax = -1e30f;
        #pragma unroll
        for (int j = 0; j < 32; ++j) {
            float dot = 0.f;
            #pragma unroll
            for (int d = 0; d < 16; ++d) {
                float4 kv = *(const float4*)&Ks[j][d * 4];   // wave-uniform addr -> broadcast
                dot += Q[d].x * kv.x + Q[d].y * kv.y + Q[d].z * kv.z + Q[d].w * kv.w;
            }
            float loc;
            if (nh < NH / 2) {
                float dxc = fabsf(qxc - bxc[j]);
                float dx1 = fabsf(qx1 - bx1[j]);
                float dx2 = fabsf(qx2 - bx2[j]);
                loc = fminf(fminf(dx1, dx2), dxc);
            } else {
                loc = fabsf(qyc - byc[j]);
            }
            float sc = dot * SCALE - loc + bmb[j];
            s[j] = sc;
            cmax = fmaxf(cmax, sc);
        }
        float mnew = fmaxf(m, cmax);
        float corr = __expf(m - mnew);   // first chunk: exp(-huge) = 0, no NaN
        lsum *= corr;
        #pragma unroll
        for (int i = 0; i < 16; ++i) {
            O[i].x *= corr; O[i].y *= corr; O[i].z *= corr; O[i].w *= corr;
        }
        #pragma unroll
        for (int j = 0; j < 32; ++j) {
            float p = __expf(s[j] - mnew);
            lsum += p;
            #pragma unroll
            for (int d = 0; d < 16; ++d) {
                float4 vv = *(const float4*)&Vs[j][d * 4];   // wave-uniform -> broadcast
                O[d].x += p * vv.x; O[d].y += p * vv.y; O[d].z += p * vv.z; O[d].w += p * vv.w;
            }
        }
        m = mnew;
        __syncthreads();
    }

    float inv = 1.0f / lsum;
    #pragma unroll
    for (int i = 0; i < 16; ++i) {
        float4 o = make_float4(O[i].x * inv, O[i].y * inv, O[i].z * inv, O[i].w * inv);
        *(float4*)&ctx[qbase + i * 4] = o;
    }
}

// ---------------- RMSNorm: out = ns * x * rsqrt(mean(x^2) + eps) ----------------
__global__ __launch_bounds__(256)
void rmsnorm_kernel(const float* __restrict__ x, const float* __restrict__ ns,
                    float* __restrict__ out)
{
    __shared__ float part[4];
    const int row = blockIdx.x;
    const int tid = threadIdx.x;
    const float* xr = x + (size_t)row * H;
    float v0 = xr[tid], v1 = xr[tid + 256], v2 = xr[tid + 512];
    float ss = v0 * v0 + v1 * v1 + v2 * v2;
    #pragma unroll
    for (int off = 32; off > 0; off >>= 1) ss += __shfl_down(ss, off);
    if ((tid & 63) == 0) part[tid >> 6] = ss;
    __syncthreads();
    float tot = part[0] + part[1] + part[2] + part[3];
    float r = rsqrtf(tot / (float)H + EPS);
    float* orow = out + (size_t)row * H;
    orow[tid]       = ns[tid]       * v0 * r;
    orow[tid + 256] = ns[tid + 256] * v1 * r;
    orow[tid + 512] = ns[tid + 512] * v2 * r;
}

// ---------------- launch ----------------
extern "C" void kernel_launch(void* const* d_in, const int* in_sizes, int n_in,
                              void* d_out, int out_size, void* d_ws, size_t ws_size,
                              hipStream_t stream)
{
    const float* hidden = (const float*)d_in[0];
    const int*   bbox   = (const int*)d_in[1];
    const int*   mask   = (const int*)d_in[2];
    const float* Wq = (const float*)d_in[3];   const float* bq = (const float*)d_in[4];
    const float* Wk = (const float*)d_in[5];   const float* bk = (const float*)d_in[6];
    const float* Wv = (const float*)d_in[7];   const float* bv = (const float*)d_in[8];
    const float* Wo = (const float*)d_in[9];   const float* bo = (const float*)d_in[10];
    const float* ns1 = (const float*)d_in[11];
    const float* W1 = (const float*)d_in[12];  const float* b1 = (const float*)d_in[13];
    const float* W2 = (const float*)d_in[14];  const float* b2 = (const float*)d_in[15];
    const float* ns2 = (const float*)d_in[16];
    float* out = (float*)d_out;

    float* w = (float*)d_ws;
    size_t o = 0;
    auto alloc = [&](size_t n) { float* p = w + o; o += n; return p; };
    float* h   = alloc((size_t)BS * H);
    float* qb  = alloc((size_t)BS * H);
    float* kb  = alloc((size_t)BS * H);
    float* vb2 = alloc((size_t)BS * H);
    float* ctx = alloc((size_t)BS * H);
    float* tmp = alloc((size_t)BS * H);
    float* act = alloc((size_t)BS * FF);
    float* st1 = alloc(BS * 32); float* ct1 = alloc(BS * 32);
    float* st2 = alloc(BS * 32); float* ct2 = alloc(BS * 32);
    float* xs1 = alloc(BS); float* xs2 = alloc(BS);
    float* xcA = alloc(BS); float* ycA = alloc(BS);
    float* mbv = alloc(BS);

    prep_kernel<<<(BS + 255) / 256, 256, 0, stream>>>(bbox, mask, st1, ct1, st2, ct2,
                                                      xs1, xs2, xcA, ycA, mbv);
    hipMemcpyAsync(h, hidden, (size_t)BS * H * sizeof(float),
                   hipMemcpyDeviceToDevice, stream);

    dim3 gH(BS / 64, H / 64);    // 64 x 12
    dim3 gF1(BS / 64, FF / 64);  // 64 x 48
    for (int l = 0; l < L; ++l) {
        const float* wq = Wq + (size_t)l * H * H;
        const float* wk = Wk + (size_t)l * H * H;
        const float* wv = Wv + (size_t)l * H * H;
        const float* wo = Wo + (size_t)l * H * H;
        const float* w1 = W1 + (size_t)l * H * FF;
        const float* w2 = W2 + (size_t)l * FF * H;

        gemm_kernel<0><<<gH, 256, 0, stream>>>(h, wq, bq + l * H, nullptr, qb, BS, H, H);
        gemm_kernel<0><<<gH, 256, 0, stream>>>(h, wk, bk + l * H, nullptr, kb, BS, H, H);
        gemm_kernel<0><<<gH, 256, 0, stream>>>(h, wv, bv + l * H, nullptr, vb2, BS, H, H);
        rope_kernel<<<(BS * NH * 32) / 256, 256, 0, stream>>>(qb, kb, st1, ct1, st2, ct2);
        attn_kernel<<<B * NH * (S / 64), 64, 0, stream>>>(qb, kb, vb2,
                                                          xs1, xs2, xcA, ycA, mbv, ctx);
        gemm_kernel<1><<<gH, 256, 0, stream>>>(ctx, wo, bo + l * H, h, tmp, BS, H, H);
        rmsnorm_kernel<<<BS, 256, 0, stream>>>(tmp, ns1 + l * H, h);
        gemm_kernel<2><<<gF1, 256, 0, stream>>>(h, w1, b1 + (size_t)l * FF, nullptr, act, BS, FF, H);
        gemm_kernel<1><<<gH, 256, 0, stream>>>(act, w2, b2 + l * H, h, tmp, BS, H, FF);
        rmsnorm_kernel<<<BS, 256, 0, stream>>>(tmp, ns2 + l * H, (l == L - 1) ? out : h);
    }
}

// Round 2
// 7039.932 us; speedup vs baseline: 6.9774x; 6.9774x over previous
//
#include <hip/hip_runtime.h>
#include <math.h>

constexpr int L = 4, H = 768, NH = 12, DH = 64, FF = 3072;
constexpr int B = 4, S = 1024;
constexpr int BS = B * S;          // 4096 token rows
constexpr float EPS = 1e-5f;
constexpr float SCALE = 0.125f;    // 1/sqrt(DH)

// ---------------- prep: RoPE tables + bbox floats + mask bias ----------------
__global__ void prep_kernel(const int* __restrict__ bbox, const int* __restrict__ mask,
                            float* __restrict__ st1, float* __restrict__ ct1,
                            float* __restrict__ st2, float* __restrict__ ct2,
                            float* __restrict__ xs1, float* __restrict__ xs2,
                            float* __restrict__ xcA, float* __restrict__ ycA,
                            float* __restrict__ mb)
{
    int idx = blockIdx.x * blockDim.x + threadIdx.x;
    if (idx >= BS) return;
    int4 bb = ((const int4*)bbox)[idx];
    float x1 = (float)bb.x, y1 = (float)bb.y, x2 = (float)bb.z, y2 = (float)bb.w;
    xs1[idx] = x1; xs2[idx] = x2;
    xcA[idx] = (x1 + x2) * 0.5f; ycA[idx] = (y1 + y2) * 0.5f;
    mb[idx] = (1.0f - (float)mask[idx]) * -10000.0f;
    #pragma unroll
    for (int fm = 0; fm < 16; ++fm) {
        // inv_freq = 10000^(-2*fm/32)
        float f = powf(10000.0f, -(float)(2 * fm) / 32.0f);
        float a;
        a = x1 * f; st1[idx*32 + 2*fm]     = sinf(a); ct1[idx*32 + 2*fm]     = cosf(a);
        a = y1 * f; st1[idx*32 + 2*fm + 1] = sinf(a); ct1[idx*32 + 2*fm + 1] = cosf(a);
        a = x2 * f; st2[idx*32 + 2*fm]     = sinf(a); ct2[idx*32 + 2*fm]     = cosf(a);
        a = y2 * f; st2[idx*32 + 2*fm + 1] = sinf(a); ct2[idx*32 + 2*fm + 1] = cosf(a);
    }
}

// ---------------- fp32 tiled GEMM: C = A(M,K) @ W(K,N) + bias [+res][+gelu] ----
// 64x64 tile, 1 wave (64 threads), 8x8 micro-tile. VALU-bound (64 FMA vs 4 ds_read_b128/kk).
// EPI: 0 = bias, 1 = bias + residual, 2 = bias + exact GELU
template<int EPI>
__global__ __launch_bounds__(64)
void gemm_kernel(const float* __restrict__ A, const float* __restrict__ W,
                 const float* __restrict__ bias, const float* __restrict__ res,
                 float* __restrict__ C, int M, int N, int K)
{
    __shared__ float As[16][68];   // [k][row], +4 pad
    __shared__ float Bs[16][68];   // [k][col]
    const int tid = threadIdx.x;
    const int row0 = blockIdx.x * 64, col0 = blockIdx.y * 64;
    const int tm = tid >> 3, tn = tid & 7;          // 8x8 thread grid
    const int ar = tid >> 2, akc = (tid & 3) * 4;   // A loads: 4 lanes/row (coalesced 64B)
    const int wr = tid >> 4, wc = (tid & 15) * 4;   // W loads: 16 lanes/row (coalesced 256B)
    float acc[8][8] = {};

    for (int k0 = 0; k0 < K; k0 += 16) {
        float4 va[4], vb[4];
        #pragma unroll
        for (int i = 0; i < 4; ++i)
            va[i] = *(const float4*)&A[(size_t)(row0 + ar + i * 16) * K + k0 + akc];
        #pragma unroll
        for (int i = 0; i < 4; ++i)
            vb[i] = *(const float4*)&W[(size_t)(k0 + wr + i * 4) * N + col0 + wc];
        __syncthreads();   // previous iteration's compute done before overwrite
        #pragma unroll
        for (int i = 0; i < 4; ++i) {
            As[akc + 0][ar + i * 16] = va[i].x;
            As[akc + 1][ar + i * 16] = va[i].y;
            As[akc + 2][ar + i * 16] = va[i].z;
            As[akc + 3][ar + i * 16] = va[i].w;
            *(float4*)&Bs[wr + i * 4][wc] = vb[i];
        }
        __syncthreads();
        #pragma unroll
        for (int kk = 0; kk < 16; ++kk) {
            float a[8], b[8];
            *(float4*)&a[0] = *(const float4*)&As[kk][tm * 8];
            *(float4*)&a[4] = *(const float4*)&As[kk][tm * 8 + 4];
            *(float4*)&b[0] = *(const float4*)&Bs[kk][tn * 8];
            *(float4*)&b[4] = *(const float4*)&Bs[kk][tn * 8 + 4];
            #pragma unroll
            for (int i = 0; i < 8; ++i)
                #pragma unroll
                for (int j = 0; j < 8; ++j)
                    acc[i][j] += a[i] * b[j];
        }
    }

    float bv[8];
    *(float4*)&bv[0] = *(const float4*)&bias[col0 + tn * 8];
    *(float4*)&bv[4] = *(const float4*)&bias[col0 + tn * 8 + 4];
    #pragma unroll
    for (int i = 0; i < 8; ++i) {
        const int r = row0 + tm * 8 + i;
        float c[8];
        #pragma unroll
        for (int j = 0; j < 8; ++j) c[j] = acc[i][j] + bv[j];
        if (EPI == 1) {
            float4 r0 = *(const float4*)&res[(size_t)r * N + col0 + tn * 8];
            float4 r1 = *(const float4*)&res[(size_t)r * N + col0 + tn * 8 + 4];
            c[0] += r0.x; c[1] += r0.y; c[2] += r0.z; c[3] += r0.w;
            c[4] += r1.x; c[5] += r1.y; c[6] += r1.z; c[7] += r1.w;
        }
        if (EPI == 2) {
            #pragma unroll
            for (int j = 0; j < 8; ++j)
                c[j] = 0.5f * c[j] * (1.0f + erff(c[j] * 0.70710678118654752f));
        }
        *(float4*)&C[(size_t)r * N + col0 + tn * 8]     = *(float4*)&c[0];
        *(float4*)&C[(size_t)r * N + col0 + tn * 8 + 4] = *(float4*)&c[4];
    }
}

// ---------------- 2D interleaved RoPE on q and k (B,S,H layout) ----------------
__global__ void rope_kernel(float* __restrict__ q, float* __restrict__ k,
                            const float* __restrict__ st1, const float* __restrict__ ct1,
                            const float* __restrict__ st2, const float* __restrict__ ct2)
{
    int tid = blockIdx.x * blockDim.x + threadIdx.x;  // over BS*NH*32 pairs
    int pr = tid & 31;
    int nh = (tid >> 5) % NH;
    int bs = tid / (32 * NH);
    const float* st = (nh & 1) ? st2 : st1;
    const float* ct = (nh & 1) ? ct2 : ct1;
    float sv = st[bs * 32 + pr], cv = ct[bs * 32 + pr];
    size_t base = (size_t)bs * H + nh * 64 + pr * 2;
    float2 qv = *(float2*)&q[base];
    float2 kv = *(float2*)&k[base];
    *(float2*)&q[base] = make_float2(qv.x * cv - qv.y * sv, qv.y * cv + qv.x * sv);
    *(float2*)&k[base] = make_float2(kv.x * cv - kv.y * sv, kv.y * cv + kv.x * sv);
}

// ---------------- flash-style attention with bbox-distance bias ----------------
// 256 threads/block = 64 q-rows; 4 lanes per q-row, each lane owns 16 dims.
// Per-thread state: Q 16 + O 16 + s 32 ~ 90 VGPR -> no scratch spill (R1 fix).
__global__ __launch_bounds__(256)
void attn_kernel(const float* __restrict__ q, const float* __restrict__ k,
                 const float* __restrict__ v,
                 const float* __restrict__ xs1, const float* __restrict__ xs2,
                 const float* __restrict__ xcA, const float* __restrict__ ycA,
                 const float* __restrict__ mb, float* __restrict__ ctx)
{
    __shared__ float Ks[32][64];
    __shared__ float Vs[32][64];
    __shared__ float bx1[32], bx2[32], bxc[32], byc[32], bmb[32];
    const int tid = threadIdx.x;
    const int qt = blockIdx.x & 15;            // S/64 = 16 q tiles
    const int nh = (blockIdx.x >> 4) % NH;
    const int b  = blockIdx.x / (16 * NH);
    const int qr = tid >> 2;                   // local q row 0..63
    const int quarter = tid & 3;               // dim quarter: quarter*16 .. +15
    const int qrow = qt * 64 + qr;
    const int bs0 = b * S;
    const size_t qbase = ((size_t)(bs0 + qrow)) * H + nh * 64 + quarter * 16;
    const bool xhead = (nh < NH / 2);

    float4 Q[4];
    #pragma unroll
    for (int i = 0; i < 4; ++i) Q[i] = *(const float4*)&q[qbase + i * 4];
    const float qx1 = xs1[bs0 + qrow], qx2 = xs2[bs0 + qrow];
    const float qxc = xcA[bs0 + qrow], qyc = ycA[bs0 + qrow];

    float m = -1e30f, lsum = 0.0f;
    float4 O[4];
    #pragma unroll
    for (int i = 0; i < 4; ++i) O[i] = make_float4(0.f, 0.f, 0.f, 0.f);

    // staging map: 8 lanes per row, each lane one float4 at c and one at c+32
    const int sr = tid >> 3, sc = (tid & 7) * 4;

    for (int kc = 0; kc < S; kc += 32) {
        const float* kp = &k[((size_t)(bs0 + kc + sr)) * H + nh * 64 + sc];
        const float* vp = &v[((size_t)(bs0 + kc + sr)) * H + nh * 64 + sc];
        *(float4*)&Ks[sr][sc]      = *(const float4*)kp;
        *(float4*)&Ks[sr][sc + 32] = *(const float4*)(kp + 32);
        *(float4*)&Vs[sr][sc]      = *(const float4*)vp;
        *(float4*)&Vs[sr][sc + 32] = *(const float4*)(vp + 32);
        if (tid < 32) {
            bx1[tid] = xs1[bs0 + kc + tid]; bx2[tid] = xs2[bs0 + kc + tid];
            bxc[tid] = xcA[bs0 + kc + tid]; byc[tid] = ycA[bs0 + kc + tid];
            bmb[tid] = mb[bs0 + kc + tid];
        }
        __syncthreads();

        float s[32];
        float cmax = -1e30f;
        #pragma unroll
        for (int j = 0; j < 32; ++j) {
            const float4* kr = (const float4*)&Ks[j][quarter * 16];
            float pd = Q[0].x * kr[0].x + Q[0].y * kr[0].y + Q[0].z * kr[0].z + Q[0].w * kr[0].w
                     + Q[1].x * kr[1].x + Q[1].y * kr[1].y + Q[1].z * kr[1].z + Q[1].w * kr[1].w
                     + Q[2].x * kr[2].x + Q[2].y * kr[2].y + Q[2].z * kr[2].z + Q[2].w * kr[2].w
                     + Q[3].x * kr[3].x + Q[3].y * kr[3].y + Q[3].z * kr[3].z + Q[3].w * kr[3].w;
            pd += __shfl_xor(pd, 1);
            pd += __shfl_xor(pd, 2);   // full 64-dim dot in all 4 quarter-lanes
            float loc;
            if (xhead) {
                float dxc = fabsf(qxc - bxc[j]);
                float dx1 = fabsf(qx1 - bx1[j]);
                float dx2 = fabsf(qx2 - bx2[j]);
                loc = fminf(fminf(dx1, dx2), dxc);
            } else {
                loc = fabsf(qyc - byc[j]);
            }
            s[j] = pd * SCALE - loc + bmb[j];
            cmax = fmaxf(cmax, s[j]);
        }
        float mnew = fmaxf(m, cmax);
        float corr = __expf(m - mnew);   // first chunk: exp(-huge) = 0
        lsum *= corr;
        #pragma unroll
        for (int i = 0; i < 4; ++i) {
            O[i].x *= corr; O[i].y *= corr; O[i].z *= corr; O[i].w *= corr;
        }
        #pragma unroll
        for (int j = 0; j < 32; ++j) {
            float p = __expf(s[j] - mnew);
            lsum += p;                     // identical across the 4 quarter-lanes
            const float4* vr = (const float4*)&Vs[j][quarter * 16];
            #pragma unroll
            for (int i = 0; i < 4; ++i) {
                O[i].x += p * vr[i].x; O[i].y += p * vr[i].y;
                O[i].z += p * vr[i].z; O[i].w += p * vr[i].w;
            }
        }
        m = mnew;
        __syncthreads();
    }

    float inv = 1.0f / lsum;
    #pragma unroll
    for (int i = 0; i < 4; ++i) {
        float4 o = make_float4(O[i].x * inv, O[i].y * inv, O[i].z * inv, O[i].w * inv);
        *(float4*)&ctx[qbase + i * 4] = o;
    }
}

// ---------------- RMSNorm: out = ns * x * rsqrt(mean(x^2) + eps) ----------------
__global__ __launch_bounds__(256)
void rmsnorm_kernel(const float* __restrict__ x, const float* __restrict__ ns,
                    float* __restrict__ out)
{
    __shared__ float part[4];
    const int row = blockIdx.x;
    const int tid = threadIdx.x;
    const float* xr = x + (size_t)row * H;
    float v0 = xr[tid], v1 = xr[tid + 256], v2 = xr[tid + 512];
    float ss = v0 * v0 + v1 * v1 + v2 * v2;
    #pragma unroll
    for (int off = 32; off > 0; off >>= 1) ss += __shfl_down(ss, off);
    if ((tid & 63) == 0) part[tid >> 6] = ss;
    __syncthreads();
    float tot = part[0] + part[1] + part[2] + part[3];
    float r = rsqrtf(tot / (float)H + EPS);
    float* orow = out + (size_t)row * H;
    orow[tid]       = ns[tid]       * v0 * r;
    orow[tid + 256] = ns[tid + 256] * v1 * r;
    orow[tid + 512] = ns[tid + 512] * v2 * r;
}

// ---------------- launch ----------------
extern "C" void kernel_launch(void* const* d_in, const int* in_sizes, int n_in,
                              void* d_out, int out_size, void* d_ws, size_t ws_size,
                              hipStream_t stream)
{
    const float* hidden = (const float*)d_in[0];
    const int*   bbox   = (const int*)d_in[1];
    const int*   mask   = (const int*)d_in[2];
    const float* Wq = (const float*)d_in[3];   const float* bq = (const float*)d_in[4];
    const float* Wk = (const float*)d_in[5];   const float* bk = (const float*)d_in[6];
    const float* Wv = (const float*)d_in[7];   const float* bv = (const float*)d_in[8];
    const float* Wo = (const float*)d_in[9];   const float* bo = (const float*)d_in[10];
    const float* ns1 = (const float*)d_in[11];
    const float* W1 = (const float*)d_in[12];  const float* b1 = (const float*)d_in[13];
    const float* W2 = (const float*)d_in[14];  const float* b2 = (const float*)d_in[15];
    const float* ns2 = (const float*)d_in[16];
    float* out = (float*)d_out;

    float* w = (float*)d_ws;
    size_t o = 0;
    auto alloc = [&](size_t n) { float* p = w + o; o += n; return p; };
    float* h   = alloc((size_t)BS * H);
    float* qb  = alloc((size_t)BS * H);
    float* kb  = alloc((size_t)BS * H);
    float* vb2 = alloc((size_t)BS * H);
    float* ctx = alloc((size_t)BS * H);
    float* tmp = alloc((size_t)BS * H);
    float* act = alloc((size_t)BS * FF);
    float* st1 = alloc(BS * 32); float* ct1 = alloc(BS * 32);
    float* st2 = alloc(BS * 32); float* ct2 = alloc(BS * 32);
    float* xs1 = alloc(BS); float* xs2 = alloc(BS);
    float* xcA = alloc(BS); float* ycA = alloc(BS);
    float* mbv = alloc(BS);

    prep_kernel<<<(BS + 255) / 256, 256, 0, stream>>>(bbox, mask, st1, ct1, st2, ct2,
                                                      xs1, xs2, xcA, ycA, mbv);
    hipMemcpyAsync(h, hidden, (size_t)BS * H * sizeof(float),
                   hipMemcpyDeviceToDevice, stream);

    dim3 gH(BS / 64, H / 64);    // 64 x 12
    dim3 gF1(BS / 64, FF / 64);  // 64 x 48
    for (int l = 0; l < L; ++l) {
        const float* wq = Wq + (size_t)l * H * H;
        const float* wk = Wk + (size_t)l * H * H;
        const float* wv = Wv + (size_t)l * H * H;
        const float* wo = Wo + (size_t)l * H * H;
        const float* w1 = W1 + (size_t)l * H * FF;
        const float* w2 = W2 + (size_t)l * FF * H;

        gemm_kernel<0><<<gH, 64, 0, stream>>>(h, wq, bq + l * H, nullptr, qb, BS, H, H);
        gemm_kernel<0><<<gH, 64, 0, stream>>>(h, wk, bk + l * H, nullptr, kb, BS, H, H);
        gemm_kernel<0><<<gH, 64, 0, stream>>>(h, wv, bv + l * H, nullptr, vb2, BS, H, H);
        rope_kernel<<<(BS * NH * 32) / 256, 256, 0, stream>>>(qb, kb, st1, ct1, st2, ct2);
        attn_kernel<<<B * NH * (S / 64), 256, 0, stream>>>(qb, kb, vb2,
                                                           xs1, xs2, xcA, ycA, mbv, ctx);
        gemm_kernel<1><<<gH, 64, 0, stream>>>(ctx, wo, bo + l * H, h, tmp, BS, H, H);
        rmsnorm_kernel<<<BS, 256, 0, stream>>>(tmp, ns1 + l * H, h);
        gemm_kernel<2><<<gF1, 64, 0, stream>>>(h, w1, b1 + (size_t)l * FF, nullptr, act, BS, FF, H);
        gemm_kernel<1><<<gH, 64, 0, stream>>>(act, w2, b2 + l * H, h, tmp, BS, H, FF);
        rmsnorm_kernel<<<BS, 256, 0, stream>>>(tmp, ns2 + l * H, (l == L - 1) ? out : h);
    }
}

// Round 6
// 3951.990 us; speedup vs baseline: 12.4293x; 1.7814x over previous
//
#include <hip/hip_runtime.h>
#include <math.h>

constexpr int L = 4, H = 768, NH = 12, DH = 64, FF = 3072;
constexpr int B = 4, S = 1024;
constexpr int BS = B * S;          // 4096 token rows
constexpr int QKVN = 3 * H;        // 2304
constexpr float EPS = 1e-5f;
constexpr float SCALE = 0.125f;    // 1/sqrt(DH)

typedef unsigned short u16;
typedef unsigned int   u32;
typedef __attribute__((ext_vector_type(8))) short bf16x8;
typedef __attribute__((ext_vector_type(4))) float f32x4;

#define GCAST(p) ((const __attribute__((address_space(1))) void*)(p))
#define LCAST(p) ((__attribute__((address_space(3))) void*)(p))

__device__ __forceinline__ u16 f2bf(float x) {
    u32 u = __float_as_uint(x);
    return (u16)((u + 0x7FFFu + ((u >> 16) & 1u)) >> 16);   // RNE
}
__device__ __forceinline__ float bf2f(u16 h) {
    return __uint_as_float(((u32)h) << 16);
}

// ---------------- prep: RoPE tables + bbox floats + mask bias ----------------
__global__ void prep_kernel(const int* __restrict__ bbox, const int* __restrict__ mask,
                            float* __restrict__ st1, float* __restrict__ ct1,
                            float* __restrict__ st2, float* __restrict__ ct2,
                            float* __restrict__ xs1, float* __restrict__ xs2,
                            float* __restrict__ xcA, float* __restrict__ ycA,
                            float* __restrict__ mb)
{
    int idx = blockIdx.x * blockDim.x + threadIdx.x;
    if (idx >= BS) return;
    int4 bb = ((const int4*)bbox)[idx];
    float x1 = (float)bb.x, y1 = (float)bb.y, x2 = (float)bb.z, y2 = (float)bb.w;
    xs1[idx] = x1; xs2[idx] = x2;
    xcA[idx] = (x1 + x2) * 0.5f; ycA[idx] = (y1 + y2) * 0.5f;
    mb[idx] = (1.0f - (float)mask[idx]) * -10000.0f;
    #pragma unroll
    for (int fm = 0; fm < 16; ++fm) {
        float f = powf(10000.0f, -(float)(2 * fm) / 32.0f);
        float a;
        a = x1 * f; st1[idx*32 + 2*fm]     = sinf(a); ct1[idx*32 + 2*fm]     = cosf(a);
        a = y1 * f; st1[idx*32 + 2*fm + 1] = sinf(a); ct1[idx*32 + 2*fm + 1] = cosf(a);
        a = x2 * f; st2[idx*32 + 2*fm]     = sinf(a); ct2[idx*32 + 2*fm]     = cosf(a);
        a = y2 * f; st2[idx*32 + 2*fm + 1] = sinf(a); ct2[idx*32 + 2*fm + 1] = cosf(a);
    }
}

// ---------------- weight transpose + bf16 hi/lo split (one layer) ----------------
// in:  W (K x N row-major fp32), out: oh/ol (N x K row-major bf16)
__global__ __launch_bounds__(256)
void wsplit_kernel(const float* __restrict__ W, u16* __restrict__ oh, u16* __restrict__ ol,
                   int K, int N)
{
    __shared__ float t[32][33];
    const int k0 = blockIdx.x * 32, n0 = blockIdx.y * 32;
    const int tr = threadIdx.x >> 5, tc = threadIdx.x & 31;   // tr 0..7
    #pragma unroll
    for (int r = 0; r < 4; ++r)
        t[tr + r * 8][tc] = W[(size_t)(k0 + tr + r * 8) * N + n0 + tc];
    __syncthreads();
    #pragma unroll
    for (int r = 0; r < 4; ++r) {
        int n = n0 + tr + r * 8, k = k0 + tc;
        float v = t[tc][tr + r * 8];
        u16 h = f2bf(v);
        size_t o = (size_t)n * K + k;
        oh[o] = h;
        ol[o] = f2bf(v - bf2f(h));
    }
}

// ---------------- elementwise fp32 -> bf16 hi/lo split ----------------
__global__ void split_kernel(const float* __restrict__ x, u16* __restrict__ oh,
                             u16* __restrict__ ol, int n)
{
    int i = blockIdx.x * blockDim.x + threadIdx.x;
    if (i >= n) return;
    float v = x[i];
    u16 h = f2bf(v);
    oh[i] = h;
    ol[i] = f2bf(v - bf2f(h));
}

// ---------------- concat q/k/v biases ----------------
__global__ void biascat_kernel(const float* __restrict__ bq, const float* __restrict__ bk,
                               const float* __restrict__ bv, float* __restrict__ o)
{
    int i = blockIdx.x * blockDim.x + threadIdx.x;
    if (i >= L * QKVN) return;
    int l = i / QKVN, j = i % QKVN;
    float v = (j < H) ? bq[l * H + j] : (j < 2 * H) ? bk[l * H + j - H] : bv[l * H + j - 2 * H];
    o[i] = v;
}

// ---------------- bf16 MFMA GEMM, 3-term split: C ~= (Ah+Al)(Wh+Wl) ----
// 128x128 tile, BK=32, 4 waves (2x2), wave = 64x64 = 4x4 frags of 16x16x32.
// A: M x K row-major bf16 (hi/lo). W: N x K row-major bf16 (transposed; hi/lo).
// EPI: 0 = +bias -> C fp32; 1 = +bias+res -> C fp32; 2 = +bias+GELU -> Oh/Ol bf16
template<int EPI>
__global__ __launch_bounds__(256)
void mgemm_kernel(const u16* __restrict__ Ah, const u16* __restrict__ Al,
                  const u16* __restrict__ Wh, const u16* __restrict__ Wl,
                  const float* __restrict__ bias, const float* __restrict__ res,
                  float* __restrict__ C, u16* __restrict__ Oh, u16* __restrict__ Ol,
                  int N, int K)
{
    __shared__ u16 As[128 * 32];   // [row][k] row-major
    __shared__ u16 Bs[128 * 32];   // [n][k]   n-major
    const int tid = threadIdx.x;
    const int wv = tid >> 6, ln = tid & 63;
    const int row0 = blockIdx.x * 128, col0 = blockIdx.y * 128;
    const int wr = wv >> 1, wc = wv & 1;
    const int lr = ln & 15, lk = (ln >> 4) * 8;
    const int srow = ln >> 2, skc = (ln & 3) * 8;   // staging: 4 lanes/row, 8 bf16 each

    f32x4 acc[4][4];
    #pragma unroll
    for (int m = 0; m < 4; ++m)
        #pragma unroll
        for (int n = 0; n < 4; ++n)
            acc[m][n] = (f32x4){0.f, 0.f, 0.f, 0.f};

    const u16* APT[3] = {Ah, Ah, Al};
    const u16* WPT[3] = {Wh, Wl, Wh};

    for (int s = 0; s < 3; ++s) {
        const u16* Ap = APT[s];
        const u16* Wp = WPT[s];
        for (int k0 = 0; k0 < K; k0 += 32) {
            #pragma unroll
            for (int i = 0; i < 2; ++i) {
                const int rr = wv * 32 + i * 16;   // 16-row group this wave stages
                const u16* ga = Ap + (size_t)(row0 + rr + srow) * K + k0 + skc;
                __builtin_amdgcn_global_load_lds(GCAST(ga), LCAST(&As[rr * 32]), 16, 0, 0);
                const u16* gb = Wp + (size_t)(col0 + rr + srow) * K + k0 + skc;
                __builtin_amdgcn_global_load_lds(GCAST(gb), LCAST(&Bs[rr * 32]), 16, 0, 0);
            }
            __syncthreads();   // drains vmcnt -> tiles visible
            bf16x8 af[4], bf[4];
            #pragma unroll
            for (int m = 0; m < 4; ++m)
                af[m] = *(const bf16x8*)&As[(wr * 64 + m * 16 + lr) * 32 + lk];
            #pragma unroll
            for (int n = 0; n < 4; ++n)
                bf[n] = *(const bf16x8*)&Bs[(wc * 64 + n * 16 + lr) * 32 + lk];
            #pragma unroll
            for (int m = 0; m < 4; ++m)
                #pragma unroll
                for (int n = 0; n < 4; ++n)
                    acc[m][n] = __builtin_amdgcn_mfma_f32_16x16x32_bf16(
                        af[m], bf[n], acc[m][n], 0, 0, 0);
            __syncthreads();   // compute done before next stage overwrites
        }
    }

    float bcol[4];
    #pragma unroll
    for (int n = 0; n < 4; ++n) bcol[n] = bias[col0 + wc * 64 + n * 16 + lr];
    #pragma unroll
    for (int m = 0; m < 4; ++m) {
        #pragma unroll
        for (int j = 0; j < 4; ++j) {
            const int r = row0 + wr * 64 + m * 16 + (ln >> 4) * 4 + j;
            #pragma unroll
            for (int n = 0; n < 4; ++n) {
                const int cidx = col0 + wc * 64 + n * 16 + lr;
                const size_t off = (size_t)r * N + cidx;
                float cv = acc[m][n][j] + bcol[n];
                if (EPI == 1) cv += res[off];
                if (EPI == 2) {
                    cv = 0.5f * cv * (1.0f + erff(cv * 0.70710678118654752f));
                    u16 h = f2bf(cv);
                    Oh[off] = h;
                    Ol[off] = f2bf(cv - bf2f(h));
                } else {
                    C[off] = cv;
                }
            }
        }
    }
}

// ---------------- 2D interleaved RoPE on q,k inside fused qkv buffer ----------------
__global__ void rope_kernel(float* __restrict__ qkv,
                            const float* __restrict__ st1, const float* __restrict__ ct1,
                            const float* __restrict__ st2, const float* __restrict__ ct2)
{
    int tid = blockIdx.x * blockDim.x + threadIdx.x;  // over BS*NH*32 pairs
    int pr = tid & 31;
    int nh = (tid >> 5) % NH;
    int bs = tid / (32 * NH);
    const float* st = (nh & 1) ? st2 : st1;
    const float* ct = (nh & 1) ? ct2 : ct1;
    float sv = st[bs * 32 + pr], cv = ct[bs * 32 + pr];
    size_t base = (size_t)bs * QKVN + nh * 64 + pr * 2;
    float2 qv = *(float2*)&qkv[base];
    float2 kv = *(float2*)&qkv[base + H];
    *(float2*)&qkv[base]     = make_float2(qv.x * cv - qv.y * sv, qv.y * cv + qv.x * sv);
    *(float2*)&qkv[base + H] = make_float2(kv.x * cv - kv.y * sv, kv.y * cv + kv.x * sv);
}

// ---------------- flash-style attention with bbox-distance bias ----------------
// 256 threads = 64 q-rows x 4 quarter-lanes (16 dims each). Writes ctx as bf16 hi/lo.
__global__ __launch_bounds__(256)
void attn_kernel(const float* __restrict__ qkv,
                 const float* __restrict__ xs1, const float* __restrict__ xs2,
                 const float* __restrict__ xcA, const float* __restrict__ ycA,
                 const float* __restrict__ mb,
                 u16* __restrict__ ctxh, u16* __restrict__ ctxl)
{
    __shared__ float Ks[32][64];
    __shared__ float Vs[32][64];
    __shared__ float bx1[32], bx2[32], bxc[32], byc[32], bmb[32];
    const int tid = threadIdx.x;
    const int qt = blockIdx.x & 15;
    const int nh = (blockIdx.x >> 4) % NH;
    const int b  = blockIdx.x / (16 * NH);
    const int qr = tid >> 2;
    const int quarter = tid & 3;
    const int qrow = qt * 64 + qr;
    const int bs0 = b * S;
    const size_t qbase = (size_t)(bs0 + qrow) * QKVN + nh * 64 + quarter * 16;
    const bool xhead = (nh < NH / 2);

    float4 Q[4];
    #pragma unroll
    for (int i = 0; i < 4; ++i) Q[i] = *(const float4*)&qkv[qbase + i * 4];
    const float qx1 = xs1[bs0 + qrow], qx2 = xs2[bs0 + qrow];
    const float qxc = xcA[bs0 + qrow], qyc = ycA[bs0 + qrow];

    float m = -1e30f, lsum = 0.0f;
    float4 O[4];
    #pragma unroll
    for (int i = 0; i < 4; ++i) O[i] = make_float4(0.f, 0.f, 0.f, 0.f);

    const int sr = tid >> 3, sc = (tid & 7) * 4;

    for (int kc = 0; kc < S; kc += 32) {
        const float* kp = &qkv[(size_t)(bs0 + kc + sr) * QKVN + H + nh * 64 + sc];
        const float* vp = &qkv[(size_t)(bs0 + kc + sr) * QKVN + 2 * H + nh * 64 + sc];
        *(float4*)&Ks[sr][sc]      = *(const float4*)kp;
        *(float4*)&Ks[sr][sc + 32] = *(const float4*)(kp + 32);
        *(float4*)&Vs[sr][sc]      = *(const float4*)vp;
        *(float4*)&Vs[sr][sc + 32] = *(const float4*)(vp + 32);
        if (tid < 32) {
            bx1[tid] = xs1[bs0 + kc + tid]; bx2[tid] = xs2[bs0 + kc + tid];
            bxc[tid] = xcA[bs0 + kc + tid]; byc[tid] = ycA[bs0 + kc + tid];
            bmb[tid] = mb[bs0 + kc + tid];
        }
        __syncthreads();

        float s[32];
        float cmax = -1e30f;
        #pragma unroll
        for (int j = 0; j < 32; ++j) {
            const float4* kr = (const float4*)&Ks[j][quarter * 16];
            float pd = Q[0].x * kr[0].x + Q[0].y * kr[0].y + Q[0].z * kr[0].z + Q[0].w * kr[0].w
                     + Q[1].x * kr[1].x + Q[1].y * kr[1].y + Q[1].z * kr[1].z + Q[1].w * kr[1].w
                     + Q[2].x * kr[2].x + Q[2].y * kr[2].y + Q[2].z * kr[2].z + Q[2].w * kr[2].w
                     + Q[3].x * kr[3].x + Q[3].y * kr[3].y + Q[3].z * kr[3].z + Q[3].w * kr[3].w;
            pd += __shfl_xor(pd, 1);
            pd += __shfl_xor(pd, 2);
            float loc;
            if (xhead) {
                float dxc = fabsf(qxc - bxc[j]);
                float dx1 = fabsf(qx1 - bx1[j]);
                float dx2 = fabsf(qx2 - bx2[j]);
                loc = fminf(fminf(dx1, dx2), dxc);
            } else {
                loc = fabsf(qyc - byc[j]);
            }
            s[j] = pd * SCALE - loc + bmb[j];
            cmax = fmaxf(cmax, s[j]);
        }
        float mnew = fmaxf(m, cmax);
        float corr = __expf(m - mnew);
        lsum *= corr;
        #pragma unroll
        for (int i = 0; i < 4; ++i) {
            O[i].x *= corr; O[i].y *= corr; O[i].z *= corr; O[i].w *= corr;
        }
        #pragma unroll
        for (int j = 0; j < 32; ++j) {
            float p = __expf(s[j] - mnew);
            lsum += p;
            const float4* vr = (const float4*)&Vs[j][quarter * 16];
            #pragma unroll
            for (int i = 0; i < 4; ++i) {
                O[i].x += p * vr[i].x; O[i].y += p * vr[i].y;
                O[i].z += p * vr[i].z; O[i].w += p * vr[i].w;
            }
        }
        m = mnew;
        __syncthreads();
    }

    float inv = 1.0f / lsum;
    u16 hb[16], lb[16];
    #pragma unroll
    for (int i = 0; i < 4; ++i) {
        float vv[4] = {O[i].x * inv, O[i].y * inv, O[i].z * inv, O[i].w * inv};
        #pragma unroll
        for (int c = 0; c < 4; ++c) {
            u16 h = f2bf(vv[c]);
            hb[i * 4 + c] = h;
            lb[i * 4 + c] = f2bf(vv[c] - bf2f(h));
        }
    }
    const size_t cb = (size_t)(bs0 + qrow) * H + nh * 64 + quarter * 16;
    *(uint4*)&ctxh[cb]     = *(uint4*)&hb[0];
    *(uint4*)&ctxh[cb + 8] = *(uint4*)&hb[8];
    *(uint4*)&ctxl[cb]     = *(uint4*)&lb[0];
    *(uint4*)&ctxl[cb + 8] = *(uint4*)&lb[8];
}

// ---------------- RMSNorm: fp32 out + bf16 hi/lo split out ----------------
__global__ __launch_bounds__(256)
void rmsnorm_kernel(const float* __restrict__ x, const float* __restrict__ ns,
                    float* __restrict__ outf, u16* __restrict__ oh, u16* __restrict__ ol)
{
    __shared__ float part[4];
    const int row = blockIdx.x;
    const int tid = threadIdx.x;
    const float* xr = x + (size_t)row * H;
    float v0 = xr[tid], v1 = xr[tid + 256], v2 = xr[tid + 512];
    float ss = v0 * v0 + v1 * v1 + v2 * v2;
    #pragma unroll
    for (int off = 32; off > 0; off >>= 1) ss += __shfl_down(ss, off);
    if ((tid & 63) == 0) part[tid >> 6] = ss;
    __syncthreads();
    float tot = part[0] + part[1] + part[2] + part[3];
    float r = rsqrtf(tot / (float)H + EPS);
    size_t base = (size_t)row * H;
    #pragma unroll
    for (int c = 0; c < 3; ++c) {
        int i = tid + c * 256;
        float v = (c == 0) ? v0 : (c == 1) ? v1 : v2;
        float y = ns[i] * v * r;
        outf[base + i] = y;
        u16 h = f2bf(y);
        oh[base + i] = h;
        ol[base + i] = f2bf(y - bf2f(h));
    }
}

// ---------------- launch ----------------
extern "C" void kernel_launch(void* const* d_in, const int* in_sizes, int n_in,
                              void* d_out, int out_size, void* d_ws, size_t ws_size,
                              hipStream_t stream)
{
    const float* hidden = (const float*)d_in[0];
    const int*   bbox   = (const int*)d_in[1];
    const int*   mask   = (const int*)d_in[2];
    const float* Wq = (const float*)d_in[3];   const float* bq = (const float*)d_in[4];
    const float* Wk = (const float*)d_in[5];   const float* bk = (const float*)d_in[6];
    const float* Wv = (const float*)d_in[7];   const float* bv = (const float*)d_in[8];
    const float* Wo = (const float*)d_in[9];   const float* bo = (const float*)d_in[10];
    const float* ns1 = (const float*)d_in[11];
    const float* W1 = (const float*)d_in[12];  const float* b1 = (const float*)d_in[13];
    const float* W2 = (const float*)d_in[14];  const float* b2 = (const float*)d_in[15];
    const float* ns2 = (const float*)d_in[16];
    float* out = (float*)d_out;

    char* w = (char*)d_ws;
    size_t o = 0;
    auto allocf = [&](size_t n) { float* p = (float*)(w + o); o += n * 4; return p; };
    auto allocu = [&](size_t n) { u16* p = (u16*)(w + o); o = (o + n * 2 + 15) & ~(size_t)15; return p; };

    float* h    = allocf((size_t)BS * H);
    float* tmp  = allocf((size_t)BS * H);
    // union region: qkv (fp32, BS*QKVN) lifetime ends at attn; act hi/lo born at FFN-up
    size_t uni_bytes = (size_t)BS * FF * 2 * 2;   // 50.3MB >= qkv's 37.7MB
    float* qkv  = (float*)(w + o);
    u16*   acth = (u16*)(w + o);
    u16*   actl = acth + (size_t)BS * FF;
    o += uni_bytes;
    u16* hh   = allocu((size_t)BS * H);   u16* hl   = allocu((size_t)BS * H);
    u16* ctxh = allocu((size_t)BS * H);   u16* ctxl = allocu((size_t)BS * H);
    u16* wqkvh = allocu((size_t)QKVN * H);  u16* wqkvl = allocu((size_t)QKVN * H);
    u16* woh   = allocu((size_t)H * H);     u16* wol   = allocu((size_t)H * H);
    u16* w1h   = allocu((size_t)FF * H);    u16* w1l   = allocu((size_t)FF * H);
    u16* w2h   = allocu((size_t)H * FF);    u16* w2l   = allocu((size_t)H * FF);
    float* st1 = allocf(BS * 32); float* ct1 = allocf(BS * 32);
    float* st2 = allocf(BS * 32); float* ct2 = allocf(BS * 32);
    float* xs1 = allocf(BS); float* xs2 = allocf(BS);
    float* xcA = allocf(BS); float* ycA = allocf(BS);
    float* mbv = allocf(BS);
    float* bqkv = allocf(L * QKVN);

    prep_kernel<<<(BS + 255) / 256, 256, 0, stream>>>(bbox, mask, st1, ct1, st2, ct2,
                                                      xs1, xs2, xcA, ycA, mbv);
    biascat_kernel<<<(L * QKVN + 255) / 256, 256, 0, stream>>>(bq, bk, bv, bqkv);
    split_kernel<<<(BS * H + 255) / 256, 256, 0, stream>>>(hidden, hh, hl, BS * H);

    for (int l = 0; l < L; ++l) {
        // per-layer weight transpose + split (keeps workspace ~131MB)
        wsplit_kernel<<<dim3(H / 32, H / 32), 256, 0, stream>>>(
            Wq + (size_t)l * H * H, wqkvh, wqkvl, H, H);
        wsplit_kernel<<<dim3(H / 32, H / 32), 256, 0, stream>>>(
            Wk + (size_t)l * H * H, wqkvh + (size_t)H * H, wqkvl + (size_t)H * H, H, H);
        wsplit_kernel<<<dim3(H / 32, H / 32), 256, 0, stream>>>(
            Wv + (size_t)l * H * H, wqkvh + (size_t)2 * H * H, wqkvl + (size_t)2 * H * H, H, H);
        wsplit_kernel<<<dim3(H / 32, H / 32), 256, 0, stream>>>(
            Wo + (size_t)l * H * H, woh, wol, H, H);
        wsplit_kernel<<<dim3(H / 32, FF / 32), 256, 0, stream>>>(
            W1 + (size_t)l * H * FF, w1h, w1l, H, FF);
        wsplit_kernel<<<dim3(FF / 32, H / 32), 256, 0, stream>>>(
            W2 + (size_t)l * FF * H, w2h, w2l, FF, H);

        // fused QKV projection: (4096 x 768) @ (768 x 2304)
        mgemm_kernel<0><<<dim3(BS / 128, QKVN / 128), 256, 0, stream>>>(
            hh, hl, wqkvh, wqkvl, bqkv + l * QKVN, nullptr, qkv, nullptr, nullptr, QKVN, H);
        rope_kernel<<<(BS * NH * 32) / 256, 256, 0, stream>>>(qkv, st1, ct1, st2, ct2);
        attn_kernel<<<B * NH * (S / 64), 256, 0, stream>>>(qkv, xs1, xs2, xcA, ycA, mbv,
                                                           ctxh, ctxl);
        // O projection + residual
        mgemm_kernel<1><<<dim3(BS / 128, H / 128), 256, 0, stream>>>(
            ctxh, ctxl, woh, wol, bo + l * H, (l == 0) ? hidden : h, tmp,
            nullptr, nullptr, H, H);
        rmsnorm_kernel<<<BS, 256, 0, stream>>>(tmp, ns1 + l * H, h, hh, hl);
        // FFN up + GELU (writes bf16 hi/lo directly; overwrites dead qkv region)
        mgemm_kernel<2><<<dim3(BS / 128, FF / 128), 256, 0, stream>>>(
            hh, hl, w1h, w1l, b1 + (size_t)l * FF, nullptr, nullptr, acth, actl, FF, H);
        // FFN down + residual
        mgemm_kernel<1><<<dim3(BS / 128, H / 128), 256, 0, stream>>>(
            acth, actl, w2h, w2l, b2 + l * H, h, tmp, nullptr, nullptr, H, FF);
        rmsnorm_kernel<<<BS, 256, 0, stream>>>(tmp, ns2 + l * H,
                                               (l == L - 1) ? out : h, hh, hl);
    }
}